// Round 1
// 86.878 us; speedup vs baseline: 1.0409x; 1.0409x over previous
//
#include <hip/hip_runtime.h>
#include <float.h>

// Problem: N=2048, F=64, K=8
//   out[m,0,f]   = x[m,f]
//   out[m,1+j,f] = j-th largest over n of adj[n,m]*x[n,f], sorted descending
//
// adj in [0,1) => product < x. Candidates are x[n,f] > 1.3 (~198/2048),
// compacted into ONE stream ordered by descending-x bucket. Group g (16
// candidates) carries bound gbnd[g] = upper x-edge of the bucket at the
// group's start: every product from position >= 16g is < gbnd[g], so a
// wave stops when all lanes' shared floor (LDS atomicMax of any wave's
// 8th-best) >= gbnd of its next group. Certificate h[7] >= 1.3 covers the
// unstored x<=1.3 tail; stream overflow (C_f > 544, ~25 sigma) falls back
// to an inline exact full rescan. Pad slots are (val=0, idx=0).
//
// topk walk is 2-deep software-pipelined: while sorting group g the 16
// adj loads of group g+4 are already in flight.

#define NN 2048
#define FF 64
#define KK 8
#define CTHRESH 1.30f
#define NB 9
#define TOT 544
#define GW 16
#define MAXG ((TOT + GW - 1) / GW)   // 34

__device__ __constant__ float d_bnd[NB] = {FLT_MAX, 2.50f, 2.25f, 2.05f, 1.90f,
                                           1.77f, 1.65f, 1.54f, 1.42f};

__device__ int2  g_pack[FF][TOT];    // (float bits of x-val, n index)
__device__ float g_gbnd[FF][MAXG];   // per-group certified upper bound
__device__ int   g_ng[FF];           // number of 16-wide groups
__device__ int   g_over[FF];         // stream overflow flag

__device__ __forceinline__ int bucket_of(float v) {
    return (v <= 2.50f) + (v <= 2.25f) + (v <= 2.05f) + (v <= 1.90f)
         + (v <= 1.77f) + (v <= 1.65f) + (v <= 1.54f) + (v <= 1.42f);
}

// ---------- Kernel A: compact x-column into one bucket-ordered stream ----------
__global__ __launch_bounds__(256) void build_buckets(const float* __restrict__ x) {
    __shared__ float xcol[NN];                 // 8 KB column stash (one global pass)
    __shared__ int   cnt[NB], cnt2[NB], off[NB + 1];
    __shared__ int2  sp[TOT];
    const int f = blockIdx.x, tid = threadIdx.x;

    if (tid < NB) { cnt[tid] = 0; cnt2[tid] = 0; }
    for (int i = tid; i < TOT; i += 256) sp[i] = make_int2(0, 0);   // safe pads
    __syncthreads();

    // pass 1: count per bucket (stash column in LDS)
    for (int n = tid; n < NN; n += 256) {
        float v = x[n * FF + f];
        xcol[n] = v;
        if (v > CTHRESH) atomicAdd(&cnt[bucket_of(v)], 1);
    }
    __syncthreads();

    // exact prefix over actual counts (no per-bucket caps)
    if (tid == 0) {
        int s = 0;
#pragma unroll
        for (int b = 0; b < NB; ++b) { off[b] = s; s += cnt[b]; }
        off[NB] = s;
        g_over[f] = (s > TOT);
        int c = s > TOT ? TOT : s;
        g_ng[f] = (c + GW - 1) / GW;
    }
    __syncthreads();

    // pass 2: place (from LDS stash)
    for (int n = tid; n < NN; n += 256) {
        float v = xcol[n];
        if (v > CTHRESH) {
            int b = bucket_of(v);
            int p = off[b] + atomicAdd(&cnt2[b], 1);
            if (p < TOT) sp[p] = make_int2(__float_as_int(v), n);
        }
    }
    __syncthreads();

    for (int i = tid; i < TOT; i += 256) g_pack[f][i] = sp[i];

    // per-group bound = bucket edge at the group's first position
    if (tid < MAXG) {
        int   pos = tid * GW;
        int   C   = off[NB];
        float bnd = 0.0f;
        if (pos < C) {
            int b = 0;
            while (b < NB - 1 && pos >= off[b + 1]) ++b;
            bnd = d_bnd[b];
        }
        g_gbnd[f][tid] = bnd;
    }
}

// ---------- sorting primitives (descending) ----------
__device__ __forceinline__ void cas(float& a, float& b) {
    float hi = fmaxf(a, b), lo = fminf(a, b);
    a = hi; b = lo;
}

// Batcher odd-even mergesort, 8 elements, 19 CAS, descending
__device__ __forceinline__ void sort8(float (&v)[8]) {
    cas(v[0],v[1]); cas(v[2],v[3]); cas(v[4],v[5]); cas(v[6],v[7]);
    cas(v[0],v[2]); cas(v[1],v[3]); cas(v[4],v[6]); cas(v[5],v[7]);
    cas(v[1],v[2]); cas(v[5],v[6]);
    cas(v[0],v[4]); cas(v[1],v[5]); cas(v[2],v[6]); cas(v[3],v[7]);
    cas(v[2],v[4]); cas(v[3],v[5]);
    cas(v[1],v[2]); cas(v[3],v[4]); cas(v[5],v[6]);
}

// h, c sorted desc -> h = top-8 of union, sorted desc (bitonic merge)
__device__ __forceinline__ void merge_top8(float (&h)[8], const float (&c)[8]) {
    float t[8];
#pragma unroll
    for (int i = 0; i < 8; ++i) t[i] = fmaxf(h[i], c[7 - i]);
    cas(t[0],t[4]); cas(t[1],t[5]); cas(t[2],t[6]); cas(t[3],t[7]);
    cas(t[0],t[2]); cas(t[1],t[3]); cas(t[4],t[6]); cas(t[5],t[7]);
    cas(t[0],t[1]); cas(t[2],t[3]); cas(t[4],t[5]); cas(t[6],t[7]);
#pragma unroll
    for (int i = 0; i < 8; ++i) h[i] = t[i];
}

// branchless sorted-desc insert (only the never-taken exact rescan)
__device__ __forceinline__ void insert8(float (&h)[KK], float v) {
#pragma unroll
    for (int j = 0; j < KK; ++j) {
        float hi = h[j];
        float mx = fmaxf(hi, v);
        v = fminf(hi, v);
        h[j] = mx;
    }
}

// ---------- Kernel B: pipelined stream-walk top-8, shared floor, tree merge ----------
// grid = (NN/64, FF); block = 256 = 4 waves over the same 64 m's
__global__ __launch_bounds__(256, 4) void topk(const float* __restrict__ x,
                                               const float* __restrict__ adj,
                                               float* __restrict__ out) {
    __shared__ int2     sc[TOT];               // staged candidate stream
    __shared__ float    sgb[MAXG];             // per-group bounds
    __shared__ unsigned sfloor[64];            // nonneg float bits, atomicMax
    __shared__ float    hm[4][KK][64];         // 8 KB
    __shared__ float    res[9][64];            // staged output rows

    const int f    = blockIdx.y;
    const int wave = threadIdx.x >> 6;
    const int lane = threadIdx.x & 63;
    const int m0   = blockIdx.x * 64;
    const int m    = m0 + lane;

    const int NG   = g_ng[f];                  // uniform
    const int over = g_over[f];
    const int lim  = NG * GW;
    for (int i = threadIdx.x; i < lim; i += 256) sc[i] = g_pack[f][i];
    if (threadIdx.x < MAXG) sgb[threadIdx.x] = g_gbnd[f][threadIdx.x];
    if (threadIdx.x < 64) sfloor[threadIdx.x] = 0u;
    __syncthreads();

    float h[KK];
#pragma unroll
    for (int j = 0; j < KK; ++j) h[j] = -FLT_MAX;

    const float* adjm = adj + m;               // lane-fixed column base

    // ---- 2-deep pipelined walk: wave w owns groups w, w+4, w+8, ... ----
    int   g = wave;
    float acur[GW], anxt[GW];
    bool  have = false;
    if (g < NG) {
        have = !__all(__uint_as_float(sfloor[lane]) >= sgb[g]);
        if (have) {
#pragma unroll
            for (int u = 0; u < GW; ++u) {
                int n = __builtin_amdgcn_readfirstlane(sc[g * GW + u].y);
                acur[u] = adjm[(size_t)n * NN];          // coalesced 256B/wave
            }
        }
    }
    while (have) {
        const int gn = g + 4;
        bool have_n = false;
        if (gn < NG) {
            have_n = !__all(__uint_as_float(sfloor[lane]) >= sgb[gn]);
            if (have_n) {
#pragma unroll
                for (int u = 0; u < GW; ++u) {           // issue next group's loads
                    int n = __builtin_amdgcn_readfirstlane(sc[gn * GW + u].y);
                    anxt[u] = adjm[(size_t)n * NN];
                }
            }
        }
        // products for current group (x-vals re-read from LDS broadcast)
        float pa[8], pb[8];
#pragma unroll
        for (int u = 0; u < 8; ++u)
            pa[u] = acur[u] * __int_as_float(sc[g * GW + u].x);
#pragma unroll
        for (int u = 0; u < 8; ++u)
            pb[u] = acur[8 + u] * __int_as_float(sc[g * GW + 8 + u].x);
        sort8(pa); sort8(pb);
        merge_top8(pa, pb);            // pa = top-8 of the 16, sorted desc
        merge_top8(h, pa);
        atomicMax(&sfloor[lane], __float_as_uint(fmaxf(h[KK - 1], 0.0f)));
#pragma unroll
        for (int u = 0; u < GW; ++u) acur[u] = anxt[u];
        g = gn; have = have_n;
    }

#pragma unroll
    for (int j = 0; j < KK; ++j) hm[wave][j][lane] = h[j];
    __syncthreads();

    // level 1: wave0 merges seg0+seg1, wave1 merges seg2+seg3 (rows sorted)
    if (wave < 2) {
        float a[KK], c[KK];
#pragma unroll
        for (int j = 0; j < KK; ++j) a[j] = hm[wave * 2][j][lane];
#pragma unroll
        for (int j = 0; j < KK; ++j) c[j] = hm[wave * 2 + 1][j][lane];
        merge_top8(a, c);
#pragma unroll
        for (int j = 0; j < KK; ++j) hm[wave * 2][j][lane] = a[j];
    }
    __syncthreads();

    // level 2: wave0 merges, certifies, stages output
    if (wave == 0) {
        float a[KK], c[KK];
#pragma unroll
        for (int j = 0; j < KK; ++j) a[j] = hm[0][j][lane];
#pragma unroll
        for (int j = 0; j < KK; ++j) c[j] = hm[2][j][lane];
        merge_top8(a, c);

        // certificate: every excluded product < CTHRESH <= a[7]
        bool ok = (!over) && (a[KK - 1] >= CTHRESH);
        if (!ok) {
            // exact full rescan — statistically never taken
#pragma unroll
            for (int j = 0; j < KK; ++j) a[j] = -FLT_MAX;
            for (int n = 0; n < NN; ++n)
                insert8(a, adj[(size_t)n * NN + m] * x[n * FF + f]);
        }

        res[0][lane] = x[m * FF + f];
#pragma unroll
        for (int j = 0; j < KK; ++j) res[1 + j][lane] = a[j];
    }
    __syncthreads();

    // distributed store of the block's 576 output words
    for (int e = threadIdx.x; e < 9 * 64; e += 256) {
        int r  = e >> 6;
        int ml = e & 63;
        out[((m0 + ml) * 9 + r) * FF + f] = res[r][ml];
    }
}

extern "C" void kernel_launch(void* const* d_in, const int* in_sizes, int n_in,
                              void* d_out, int out_size, void* d_ws, size_t ws_size,
                              hipStream_t stream) {
    const float* x   = (const float*)d_in[0];   // [2048, 64]
    const float* adj = (const float*)d_in[1];   // [2048, 2048]
    float* out = (float*)d_out;                 // [2048, 9, 64]

    build_buckets<<<FF, 256, 0, stream>>>(x);

    dim3 grid2(NN / 64, FF);
    topk<<<grid2, 256, 0, stream>>>(x, adj, out);
}